// Round 4
// baseline (290.037 us; speedup 1.0000x reference)
//
#include <hip/hip_runtime.h>

// GraphSAGE 2-layer + linear head, N=50000, E=600000, C=128 everywhere.
// R13: raise gather-phase concurrency. R12 counters (first per-dispatch data
//      for the dominant phase): fused<true> 55us, MfmaUtil 4.4, VALU 22.6,
//      Occ 29%, hbm 1.6TB/s => latency-bound, occupancy-starved; LDS 32KB
//      capped residency at 5 blocks/CU. Change: B-stage 16KB -> 8KB (one
//      kk per round, 8 rounds, paired barriers) => LDS 16KB(!HEAD)/24KB(HEAD)
//      => 8/6 blocks/CU; launch_bounds(256,8) pins VGPR<=64 (natural alloc
//      is already 64). Agg inner body untouched (ledger). Decision rule:
//      if fused kernels improve but total stays >=218, a ~85us fixed cost
//      (2x 42us ws-fill?) sits in the timed window -> attack that next.
// Ledger: R10 gemm-fusion NEUTRAL; R11 Wt3-staging -3 (L2 ~3us/100MB);
//      R12 agg+gemm fusion NEUTRAL total but unlocked counters. Agg: fp8
//      NEUTRAL, ILP NEUTRAL, XCD-slice NEGATIVE.

typedef _Float16 f16;
typedef unsigned int u32;
typedef __attribute__((ext_vector_type(4))) _Float16 f16x4;
typedef __attribute__((ext_vector_type(8))) _Float16 f16x8;
typedef __attribute__((ext_vector_type(4))) float f32x4;

#define RNB 128   // radix blocks (256 bins x 128 = 32768 hist entries)

// ---- prep: [0,cb) convert x -> f16 | [cb,cb+wb) weights | rest: radix hist
// weights k-chunked transposed, 3 tables contiguous (32768 f16 each):
// wt[w][(chunk*128 + n)*8 + j] = W_w[k=chunk*8+j][n], W = [WA;WB] stacked.
__global__ void prep_kernel(const float* __restrict__ x, f16* __restrict__ xh, int n4,
                            const int* __restrict__ ei, int* __restrict__ ghist, int E,
                            const float* __restrict__ W1l, const float* __restrict__ W1r,
                            const float* __restrict__ W2l, const float* __restrict__ W2r,
                            const float* __restrict__ Wlin, f16* __restrict__ wt,
                            int cb, int wb) {
  int b = blockIdx.x;
  if (b < cb) {
    int i = b * 256 + threadIdx.x;
    if (i < n4) {
      const float4 v = ((const float4*)x)[i];
      f16x4 h = { (f16)v.x, (f16)v.y, (f16)v.z, (f16)v.w };
      ((f16x4*)xh)[i] = h;
    }
  } else if (b < cb + wb) {
    int tid = (b - cb) * 256 + threadIdx.x;   // 0 .. 3*32768
    int w = tid >> 15, idx = tid & 32767;
    int j = idx & 7, n = (idx >> 3) & 127, chunk = idx >> 10;
    int k = chunk * 8 + j;
    float v;
    if (w == 0) v = (k < 128) ? W1l[k * 128 + n] : W1r[(k - 128) * 128 + n];
    else if (w == 1) v = (k < 128) ? W2l[k * 128 + n] : W2r[(k - 128) * 128 + n];
    else v = Wlin[k * 128 + n];
    wt[tid] = (f16)v;
  } else {
    __shared__ int h[256];
    int tid = threadIdx.x, rb = b - cb - wb;   // 0..RNB-1
    h[tid] = 0;
    __syncthreads();
    int per = (E + RNB - 1) / RNB;
    int s = rb * per, e = s + per; if (e > E) e = E;
    for (int i = s + tid; i < e; i += 256) atomicAdd(&h[ei[E + i] >> 8], 1);
    __syncthreads();
    ghist[tid * RNB + rb] = h[tid];
  }
}

// shfl-based exclusive scan over 256 threads (4 waves); one barrier.
__device__ inline int block_excl_scan256(int v, int* ws) {
  int lane = threadIdx.x & 63, w = threadIdx.x >> 6;
  int incl = v;
#pragma unroll
  for (int o = 1; o < 64; o <<= 1) {
    int u = __shfl_up(incl, o);
    if (lane >= o) incl += u;
  }
  if (lane == 63) ws[w] = incl;
  __syncthreads();
  int base = 0;
#pragma unroll
  for (int i = 0; i < 4; ++i) base += (i < w) ? ws[i] : 0;
  return base + incl - v;
}

// deterministic scatter into per-(block,bin) ranges; LDS cursors only.
__global__ void radix_scatter(const int* __restrict__ ei, const int* __restrict__ ghist,
                              u32* __restrict__ tmp, int E) {
  __shared__ int cur[256];
  __shared__ int ws[4];
  int tid = threadIdx.x, b = blockIdx.x;
  const int* row = ghist + tid * RNB;
  int part = 0, rest = 0;
  for (int i = 0; i < b; ++i) part += row[i];
  for (int i = b; i < RNB; ++i) rest += row[i];
  int total = part + rest;
  int excl = block_excl_scan256(total, ws);
  cur[tid] = excl + part;
  __syncthreads();
  int per = (E + RNB - 1) / RNB;
  int s = b * per, e = s + per; if (e > E) e = E;
  for (int i = s + tid; i < e; i += 256) {
    int d = ei[E + i], sr = ei[i];
    int pos = atomicAdd(&cur[d >> 8], 1);
    tmp[pos] = ((u32)sr << 8) | (u32)(d & 255);
  }
}

// one block per high-byte bucket: LDS low-byte hist + scan -> off[] + srcs.
__global__ void radix_bucket(const u32* __restrict__ tmp, const int* __restrict__ ghist,
                             int* __restrict__ srcs, int* __restrict__ off,
                             int N, int E, int HB) {
  __shared__ int h[256], sc[256], cur[256];
  __shared__ int bsc[257];
  __shared__ int ws[4];
  int tid = threadIdx.x, hb = blockIdx.x;
  const int* row = ghist + tid * RNB;
  int total = 0;
#pragma unroll 4
  for (int i = 0; i < RNB; ++i) total += row[i];
  int excl = block_excl_scan256(total, ws);
  bsc[tid] = excl;
  if (tid == 255) bsc[256] = E;
  h[tid] = 0;
  __syncthreads();
  int start = bsc[hb];
  int end = bsc[hb + 1];
  for (int i = start + tid; i < end; i += 256) atomicAdd(&h[tmp[i] & 255u], 1);
  __syncthreads();
  sc[tid] = h[tid];
  __syncthreads();
  for (int o = 1; o < 256; o <<= 1) {
    int u = (tid >= o) ? sc[tid - o] : 0;
    __syncthreads();
    sc[tid] += u;
    __syncthreads();
  }
  int exclb = sc[tid] - h[tid];
  int v = (hb << 8) + tid;
  if (v < N) off[v] = start + exclb;
  if (hb == 0 && tid == 0) off[N] = E;
  cur[tid] = start + exclb;
  __syncthreads();
  for (int i = start + tid; i < end; i += 256) {
    u32 p = tmp[i];
    int pos = atomicAdd(&cur[p & 255u], 1);
    srcs[pos] = (int)(p >> 8);
  }
}

// ---- FUSED per-layer kernel: block = 32 consecutive nodes, 4 waves.
// Phase A (agg, R3-proven inner body): 4 passes, wave handles node pair
//   (p*8 + wave*2); mean -> 8KB XOR-swizzled LDS tile.
// Phase B (gemm): out32x128 = act([mean|feat] @ WtA + bA); B streamed via
//   8KB LDS rounds (one kk each, paired barriers). HEAD additionally does
//   out = [feat|x2] @ WtB + bB, x2 through a second 8KB swizzled tile,
//   feat A-frags reused in-register.
// LDS (f16 units): B-stage [0,4096) | mean [4096,8192) | x2 [8192,12288).
// Totals: !HEAD 16KB -> 8 blocks/CU; HEAD 24KB -> 6 blocks/CU. VGPR<=64.
#define AGG_R 6
template <bool HEAD>
__global__ __launch_bounds__(256, 8) void fused_kernel(
    const f16* __restrict__ feat,   // gather source AND root operand (xh / x1h)
    const int* __restrict__ off, const int* __restrict__ srcs,
    const f16* __restrict__ WtA, const f16* __restrict__ WtB,
    const float* __restrict__ bA, const float* __restrict__ bB,
    void* __restrict__ outp, int n) {
  __shared__ f16 lds[HEAD ? 12288 : 8192];
  int tid = threadIdx.x;
  int wave = tid >> 6, lane = tid & 63;
  int sub = lane >> 4, n15 = lane & 15;
  int base = blockIdx.x * 32;

  // stage round 0 of WtA (chunks 0..3) early; covered by the post-agg barrier
  ((f16x8*)lds)[tid]       = ((const f16x8*)WtA)[tid];
  ((f16x8*)lds)[256 + tid] = ((const f16x8*)WtA)[256 + tid];

  // ---- Phase A: aggregate 32 nodes (4 passes x 4 waves x 2 nodes)
#pragma unroll 1
  for (int p = 0; p < 4; ++p) {
    int ln0 = p * 8 + wave * 2;
    int w0 = base + ln0, w1 = w0 + 1;
    bool a0 = w0 < n, a1 = w1 < n;
    int beg0 = a0 ? off[w0] : 0;
    int end0 = a0 ? off[w0 + 1] : 0;
    int beg1 = end0;                       // CSR contiguity
    int end1 = a1 ? off[w1 + 1] : end0;
    int deg0 = end0 - beg0, deg1 = end1 - beg1;

    int s0[AGG_R], s1[AGG_R];
    bool v0[AGG_R], v1[AGG_R];
#pragma unroll
    for (int k = 0; k < AGG_R; ++k) {
      int pp = 4 * k + sub;
      v0[k] = pp < deg0;  s0[k] = v0[k] ? srcs[beg0 + pp] : 0;
      v1[k] = pp < deg1;  s1[k] = v1[k] ? srcs[beg1 + pp] : 0;
    }
    f16x8 g0[AGG_R], g1[AGG_R];
#pragma unroll
    for (int k = 0; k < AGG_R; ++k) {
      if (v0[k]) g0[k] = *(const f16x8*)(feat + (size_t)s0[k] * 128 + n15 * 8);
      if (v1[k]) g1[k] = *(const f16x8*)(feat + (size_t)s1[k] * 128 + n15 * 8);
    }
    float acc0[8] = {}, acc1[8] = {};
#pragma unroll
    for (int k = 0; k < AGG_R; ++k) {
      if (v0[k]) {
#pragma unroll
        for (int j = 0; j < 8; ++j) acc0[j] += (float)g0[k][j];
      }
      if (v1[k]) {
#pragma unroll
        for (int j = 0; j < 8; ++j) acc1[j] += (float)g1[k][j];
      }
    }
    for (int e = beg0 + 4 * AGG_R; e < end0; e += 4) {   // rare deg>24 tail
      if (sub < end0 - e) {
        int s = srcs[e + sub];
        f16x8 g = *(const f16x8*)(feat + (size_t)s * 128 + n15 * 8);
#pragma unroll
        for (int j = 0; j < 8; ++j) acc0[j] += (float)g[j];
      }
    }
    for (int e = beg1 + 4 * AGG_R; e < end1; e += 4) {
      if (sub < end1 - e) {
        int s = srcs[e + sub];
        f16x8 g = *(const f16x8*)(feat + (size_t)s * 128 + n15 * 8);
#pragma unroll
        for (int j = 0; j < 8; ++j) acc1[j] += (float)g[j];
      }
    }
#pragma unroll
    for (int j = 0; j < 8; ++j) {
      acc0[j] += __shfl_xor(acc0[j], 16);
      acc0[j] += __shfl_xor(acc0[j], 32);
      acc1[j] += __shfl_xor(acc1[j], 16);
      acc1[j] += __shfl_xor(acc1[j], 32);
    }
    if (sub == 0) {
      float inv = 1.0f / fmaxf((float)deg0, 1.0f);
      f16x8 o;
#pragma unroll
      for (int j = 0; j < 8; ++j) o[j] = (f16)(acc0[j] * inv);
      *(f16x8*)(lds + 4096 + ln0 * 128 + ((n15 ^ (ln0 & 15)) << 3)) = o;
    } else if (sub == 1) {
      float inv = 1.0f / fmaxf((float)deg1, 1.0f);
      int ln1 = ln0 + 1;
      f16x8 o;
#pragma unroll
      for (int j = 0; j < 8; ++j) o[j] = (f16)(acc1[j] * inv);
      *(f16x8*)(lds + 4096 + ln1 * 128 + ((n15 ^ (ln1 & 15)) << 3)) = o;
    }
  }
  __syncthreads();   // means + stage round 0 visible

  // ---- Phase B: gemm. wave -> (rowgroup rg, colhalf ch); 16 rows x 64 cols.
  int rg = wave & 1, ch = wave >> 1;
  int rowl = rg * 16 + n15;
  int colb = ch * 64;

  f16x8 a[8];
#pragma unroll
  for (int kk = 0; kk < 4; ++kk)    // mean part (k 0..127) from swizzled LDS
    a[kk] = *(const f16x8*)(lds + 4096 + rowl * 128 + (((kk * 4 + sub) ^ n15) << 3));
  {
    int node = base + rowl; if (node >= n) node = n - 1;   // clamped tail load
    const f16* bp = feat + (size_t)node * 128 + sub * 8;
#pragma unroll
    for (int kk = 4; kk < 8; ++kk) a[kk] = *(const f16x8*)(bp + (kk - 4) * 32);
  }

  f32x4 acc[4] = {};
#pragma unroll
  for (int q = 0; q < 8; ++q) {
    if (q) {
      __syncthreads();   // all waves done with previous round's B
      ((f16x8*)lds)[tid]       = ((const f16x8*)WtA)[q * 512 + tid];
      ((f16x8*)lds)[256 + tid] = ((const f16x8*)WtA)[q * 512 + 256 + tid];
      __syncthreads();   // round q staged
    }
#pragma unroll
    for (int t = 0; t < 4; ++t) {
      f16x8 bfr = ((const f16x8*)lds)[sub * 128 + colb + t * 16 + n15];
      acc[t] = __builtin_amdgcn_mfma_f32_16x16x32_f16(a[q], bfr, acc[t], 0, 0, 0);
    }
  }

  if (!HEAD) {
    // epilogue: x1 = relu(acc + bA) -> f16 out
#pragma unroll
    for (int t = 0; t < 4; ++t) {
      float bv = bA[colb + t * 16 + n15];
#pragma unroll
      for (int i = 0; i < 4; ++i) {
        int row = base + rg * 16 + sub * 4 + i;
        if (row < n) {
          float v = fmaxf(acc[t][i] + bv, 0.f);
          ((f16*)outp)[(size_t)row * 128 + colb + t * 16 + n15] = (f16)v;
        }
      }
    }
  } else {
    // x2 = relu(acc + bA) -> swizzled LDS tile (own region; no conflict)
#pragma unroll
    for (int t = 0; t < 4; ++t) {
      float bv = bA[colb + t * 16 + n15];
      int col = colb + t * 16 + n15;
      int cchunk = col >> 3, coff = col & 7;
#pragma unroll
      for (int i = 0; i < 4; ++i) {
        int rw = rg * 16 + sub * 4 + i;
        float v = fmaxf(acc[t][i] + bv, 0.f);
        lds[8192 + rw * 128 + (((cchunk ^ (rw & 15)) << 3) | coff)] = (f16)v;
      }
    }
    __syncthreads();   // B region free (all mfma(7) reads done); x2 visible
    ((f16x8*)lds)[tid]       = ((const f16x8*)WtB)[tid];
    ((f16x8*)lds)[256 + tid] = ((const f16x8*)WtB)[256 + tid];
    __syncthreads();   // WtB round 0 staged

    f16x8 a2[4];
#pragma unroll
    for (int kk2 = 0; kk2 < 4; ++kk2)
      a2[kk2] = *(const f16x8*)(lds + 8192 + rowl * 128 + (((kk2 * 4 + sub) ^ n15) << 3));

    f32x4 acc3[4] = {};
#pragma unroll
    for (int q = 0; q < 8; ++q) {
      if (q) {
        __syncthreads();
        ((f16x8*)lds)[tid]       = ((const f16x8*)WtB)[q * 512 + tid];
        ((f16x8*)lds)[256 + tid] = ((const f16x8*)WtB)[q * 512 + 256 + tid];
        __syncthreads();
      }
#pragma unroll
      for (int t = 0; t < 4; ++t) {
        f16x8 bfr = ((const f16x8*)lds)[sub * 128 + colb + t * 16 + n15];
        f16x8 av = (q < 4) ? a[4 + q] : a2[q - 4];   // [x1 | x2]
        acc3[t] = __builtin_amdgcn_mfma_f32_16x16x32_f16(av, bfr, acc3[t], 0, 0, 0);
      }
    }
#pragma unroll
    for (int t = 0; t < 4; ++t) {
      float bv = bB[colb + t * 16 + n15];
#pragma unroll
      for (int i = 0; i < 4; ++i) {
        int row = base + rg * 16 + sub * 4 + i;
        if (row < n)
          ((float*)outp)[(size_t)row * 128 + colb + t * 16 + n15] = acc3[t][i] + bv;
      }
    }
  }
}

extern "C" void kernel_launch(void* const* d_in, const int* in_sizes, int n_in,
                              void* d_out, int out_size, void* d_ws, size_t ws_size,
                              hipStream_t stream) {
  (void)n_in; (void)out_size; (void)ws_size;
  const float* x    = (const float*)d_in[0];
  const int*   ei   = (const int*)d_in[1];
  const float* W1l  = (const float*)d_in[2];
  const float* b1l  = (const float*)d_in[3];
  const float* W1r  = (const float*)d_in[4];
  const float* W2l  = (const float*)d_in[5];
  const float* b2l  = (const float*)d_in[6];
  const float* W2r  = (const float*)d_in[7];
  const float* Wlin = (const float*)d_in[8];
  const float* blin = (const float*)d_in[9];
  const int N = in_sizes[0] / 128;
  const int E = in_sizes[1] / 2;

  char* ws = (char*)d_ws;
  size_t o = 0;
  auto alloc = [&](size_t bytes) {
    char* p = ws + o;
    o = (o + bytes + 255) & ~(size_t)255;
    return p;
  };
  f16*  xh   = (f16*)alloc((size_t)N * 128 * 2);
  f16*  x1h  = (f16*)alloc((size_t)N * 128 * 2);
  f16*  wt   = (f16*)alloc((size_t)3 * 32768 * 2);   // wt1|wt2|wt3 contiguous
  int*  off  = (int*)alloc(((size_t)N + 1) * 4);
  int*  srcs = (int*)alloc((size_t)E * 4);
  u32*  tmp  = (u32*)alloc((size_t)E * 4);           // packed (src<<8)|dstLow
  int*  ghist= (int*)alloc(256 * RNB * 4);
  f16* wt1 = wt, *wt2 = wt + 32768, *wt3 = wt + 65536;

  const int n4 = N * 128 / 4;
  const int cb = (n4 + 255) / 256;           // convert blocks
  const int wb = (3 * 32768) / 256;          // weight blocks (384)
  const int HB = (N + 255) / 256;            // high-byte buckets (196)

  // prep (convert + weights + radix hist)
  prep_kernel<<<cb + wb + RNB, 256, 0, stream>>>(x, xh, n4, ei, ghist, E,
                                                 W1l, W1r, W2l, W2r, Wlin, wt, cb, wb);
  // CSR build (atomic-free; global prefix rebuilt inline)
  radix_scatter<<<RNB, 256, 0, stream>>>(ei, ghist, tmp, E);
  radix_bucket<<<HB, 256, 0, stream>>>(tmp, ghist, srcs, off, N, E, HB);

  const int fusedBlocks = (N + 31) / 32;     // 1563

  // layer 1 fused: x1 = relu(mean(x) @ W1_l + x @ W1_r + b1)
  fused_kernel<false><<<fusedBlocks, 256, 0, stream>>>(
      xh, off, srcs, wt1, (const f16*)nullptr, b1l, (const float*)nullptr, x1h, N);
  // layer 2 + head fused: x2 = relu(mean(x1) @ W2 + b2); out = [x1|x2] @ W3 + b3
  fused_kernel<true><<<fusedBlocks, 256, 0, stream>>>(
      x1h, off, srcs, wt2, wt3, b2l, blin, d_out, N);
}

// Round 5
// 249.955 us; speedup vs baseline: 1.1604x; 1.1604x over previous
//
#include <hip/hip_runtime.h>

// GraphSAGE 2-layer + linear head, N=50000, E=600000, C=128 everywhere.
// R14: fix R13's spill disaster. R13 counters: VGPR 32 (launch_bounds(256,8)
//      pinned unified VGPR+AGPR to 64 => ~128MB scratch round-trips,
//      WRITE_SIZE 25->152MB, dur 2x). Demand is ~100 regs. Change ONLY the
//      bound: (256,8) -> (256,5) => VGPR cap ~102 (natural alloc 64, no
//      spill), static cap 5 blocks/CU (20 waves, 62.5%) vs R12's 4 (50%).
//      LDS stays 16KB(!HEAD)/24KB(HEAD) from R13 so LDS never binds.
//      Clean A/B on the occupancy theory. Decision rule: if spills gone but
//      Occ ~29% and durs ~R12 => static-cap theory dead -> de-fuse agg
//      (standalone agg was ~4TB/s vs 1.65 fused), keep gemm23 fusion only.
// Fill-floor note: 2x ~43us harness ws-fills sit in the timed window =>
//      ~86us fixed; our controllable portion is ~140us (aggs ~76 dominant).
// Ledger: R10 gemm-fusion NEUTRAL; R11 Wt3-staging -3 (L2 ~3us/100MB);
//      R12 agg+gemm fusion NEUTRAL total, unlocked counters; R13 (256,8)
//      SPILL REGRESSION. Agg: fp8 NEUTRAL, ILP NEUTRAL, XCD-slice NEGATIVE.

typedef _Float16 f16;
typedef unsigned int u32;
typedef __attribute__((ext_vector_type(4))) _Float16 f16x4;
typedef __attribute__((ext_vector_type(8))) _Float16 f16x8;
typedef __attribute__((ext_vector_type(4))) float f32x4;

#define RNB 128   // radix blocks (256 bins x 128 = 32768 hist entries)

// ---- prep: [0,cb) convert x -> f16 | [cb,cb+wb) weights | rest: radix hist
// weights k-chunked transposed, 3 tables contiguous (32768 f16 each):
// wt[w][(chunk*128 + n)*8 + j] = W_w[k=chunk*8+j][n], W = [WA;WB] stacked.
__global__ void prep_kernel(const float* __restrict__ x, f16* __restrict__ xh, int n4,
                            const int* __restrict__ ei, int* __restrict__ ghist, int E,
                            const float* __restrict__ W1l, const float* __restrict__ W1r,
                            const float* __restrict__ W2l, const float* __restrict__ W2r,
                            const float* __restrict__ Wlin, f16* __restrict__ wt,
                            int cb, int wb) {
  int b = blockIdx.x;
  if (b < cb) {
    int i = b * 256 + threadIdx.x;
    if (i < n4) {
      const float4 v = ((const float4*)x)[i];
      f16x4 h = { (f16)v.x, (f16)v.y, (f16)v.z, (f16)v.w };
      ((f16x4*)xh)[i] = h;
    }
  } else if (b < cb + wb) {
    int tid = (b - cb) * 256 + threadIdx.x;   // 0 .. 3*32768
    int w = tid >> 15, idx = tid & 32767;
    int j = idx & 7, n = (idx >> 3) & 127, chunk = idx >> 10;
    int k = chunk * 8 + j;
    float v;
    if (w == 0) v = (k < 128) ? W1l[k * 128 + n] : W1r[(k - 128) * 128 + n];
    else if (w == 1) v = (k < 128) ? W2l[k * 128 + n] : W2r[(k - 128) * 128 + n];
    else v = Wlin[k * 128 + n];
    wt[tid] = (f16)v;
  } else {
    __shared__ int h[256];
    int tid = threadIdx.x, rb = b - cb - wb;   // 0..RNB-1
    h[tid] = 0;
    __syncthreads();
    int per = (E + RNB - 1) / RNB;
    int s = rb * per, e = s + per; if (e > E) e = E;
    for (int i = s + tid; i < e; i += 256) atomicAdd(&h[ei[E + i] >> 8], 1);
    __syncthreads();
    ghist[tid * RNB + rb] = h[tid];
  }
}

// shfl-based exclusive scan over 256 threads (4 waves); one barrier.
__device__ inline int block_excl_scan256(int v, int* ws) {
  int lane = threadIdx.x & 63, w = threadIdx.x >> 6;
  int incl = v;
#pragma unroll
  for (int o = 1; o < 64; o <<= 1) {
    int u = __shfl_up(incl, o);
    if (lane >= o) incl += u;
  }
  if (lane == 63) ws[w] = incl;
  __syncthreads();
  int base = 0;
#pragma unroll
  for (int i = 0; i < 4; ++i) base += (i < w) ? ws[i] : 0;
  return base + incl - v;
}

// deterministic scatter into per-(block,bin) ranges; LDS cursors only.
__global__ void radix_scatter(const int* __restrict__ ei, const int* __restrict__ ghist,
                              u32* __restrict__ tmp, int E) {
  __shared__ int cur[256];
  __shared__ int ws[4];
  int tid = threadIdx.x, b = blockIdx.x;
  const int* row = ghist + tid * RNB;
  int part = 0, rest = 0;
  for (int i = 0; i < b; ++i) part += row[i];
  for (int i = b; i < RNB; ++i) rest += row[i];
  int total = part + rest;
  int excl = block_excl_scan256(total, ws);
  cur[tid] = excl + part;
  __syncthreads();
  int per = (E + RNB - 1) / RNB;
  int s = b * per, e = s + per; if (e > E) e = E;
  for (int i = s + tid; i < e; i += 256) {
    int d = ei[E + i], sr = ei[i];
    int pos = atomicAdd(&cur[d >> 8], 1);
    tmp[pos] = ((u32)sr << 8) | (u32)(d & 255);
  }
}

// one block per high-byte bucket: LDS low-byte hist + scan -> off[] + srcs.
__global__ void radix_bucket(const u32* __restrict__ tmp, const int* __restrict__ ghist,
                             int* __restrict__ srcs, int* __restrict__ off,
                             int N, int E, int HB) {
  __shared__ int h[256], sc[256], cur[256];
  __shared__ int bsc[257];
  __shared__ int ws[4];
  int tid = threadIdx.x, hb = blockIdx.x;
  const int* row = ghist + tid * RNB;
  int total = 0;
#pragma unroll 4
  for (int i = 0; i < RNB; ++i) total += row[i];
  int excl = block_excl_scan256(total, ws);
  bsc[tid] = excl;
  if (tid == 255) bsc[256] = E;
  h[tid] = 0;
  __syncthreads();
  int start = bsc[hb];
  int end = bsc[hb + 1];
  for (int i = start + tid; i < end; i += 256) atomicAdd(&h[tmp[i] & 255u], 1);
  __syncthreads();
  sc[tid] = h[tid];
  __syncthreads();
  for (int o = 1; o < 256; o <<= 1) {
    int u = (tid >= o) ? sc[tid - o] : 0;
    __syncthreads();
    sc[tid] += u;
    __syncthreads();
  }
  int exclb = sc[tid] - h[tid];
  int v = (hb << 8) + tid;
  if (v < N) off[v] = start + exclb;
  if (hb == 0 && tid == 0) off[N] = E;
  cur[tid] = start + exclb;
  __syncthreads();
  for (int i = start + tid; i < end; i += 256) {
    u32 p = tmp[i];
    int pos = atomicAdd(&cur[p & 255u], 1);
    srcs[pos] = (int)(p >> 8);
  }
}

// ---- FUSED per-layer kernel: block = 32 consecutive nodes, 4 waves.
// Phase A (agg, R3-proven inner body): 4 passes, wave handles node pair
//   (p*8 + wave*2); mean -> 8KB XOR-swizzled LDS tile.
// Phase B (gemm): out32x128 = act([mean|feat] @ WtA + bA); B streamed via
//   8KB LDS rounds (one kk each, paired barriers). HEAD additionally does
//   out = [feat|x2] @ WtB + bB, x2 through a second 8KB swizzled tile,
//   feat A-frags reused in-register.
// LDS (f16 units): B-stage [0,4096) | mean [4096,8192) | x2 [8192,12288).
// Totals: !HEAD 16KB / HEAD 24KB. launch_bounds(256,5): 5 blocks/CU static,
// VGPR cap ~102 (natural alloc 64 => no spill; R13's (256,8) spilled).
#define AGG_R 6
template <bool HEAD>
__global__ __launch_bounds__(256, 5) void fused_kernel(
    const f16* __restrict__ feat,   // gather source AND root operand (xh / x1h)
    const int* __restrict__ off, const int* __restrict__ srcs,
    const f16* __restrict__ WtA, const f16* __restrict__ WtB,
    const float* __restrict__ bA, const float* __restrict__ bB,
    void* __restrict__ outp, int n) {
  __shared__ f16 lds[HEAD ? 12288 : 8192];
  int tid = threadIdx.x;
  int wave = tid >> 6, lane = tid & 63;
  int sub = lane >> 4, n15 = lane & 15;
  int base = blockIdx.x * 32;

  // stage round 0 of WtA (chunks 0..3) early; covered by the post-agg barrier
  ((f16x8*)lds)[tid]       = ((const f16x8*)WtA)[tid];
  ((f16x8*)lds)[256 + tid] = ((const f16x8*)WtA)[256 + tid];

  // ---- Phase A: aggregate 32 nodes (4 passes x 4 waves x 2 nodes)
#pragma unroll 1
  for (int p = 0; p < 4; ++p) {
    int ln0 = p * 8 + wave * 2;
    int w0 = base + ln0, w1 = w0 + 1;
    bool a0 = w0 < n, a1 = w1 < n;
    int beg0 = a0 ? off[w0] : 0;
    int end0 = a0 ? off[w0 + 1] : 0;
    int beg1 = end0;                       // CSR contiguity
    int end1 = a1 ? off[w1 + 1] : end0;
    int deg0 = end0 - beg0, deg1 = end1 - beg1;

    int s0[AGG_R], s1[AGG_R];
    bool v0[AGG_R], v1[AGG_R];
#pragma unroll
    for (int k = 0; k < AGG_R; ++k) {
      int pp = 4 * k + sub;
      v0[k] = pp < deg0;  s0[k] = v0[k] ? srcs[beg0 + pp] : 0;
      v1[k] = pp < deg1;  s1[k] = v1[k] ? srcs[beg1 + pp] : 0;
    }
    f16x8 g0[AGG_R], g1[AGG_R];
#pragma unroll
    for (int k = 0; k < AGG_R; ++k) {
      if (v0[k]) g0[k] = *(const f16x8*)(feat + (size_t)s0[k] * 128 + n15 * 8);
      if (v1[k]) g1[k] = *(const f16x8*)(feat + (size_t)s1[k] * 128 + n15 * 8);
    }
    float acc0[8] = {}, acc1[8] = {};
#pragma unroll
    for (int k = 0; k < AGG_R; ++k) {
      if (v0[k]) {
#pragma unroll
        for (int j = 0; j < 8; ++j) acc0[j] += (float)g0[k][j];
      }
      if (v1[k]) {
#pragma unroll
        for (int j = 0; j < 8; ++j) acc1[j] += (float)g1[k][j];
      }
    }
    for (int e = beg0 + 4 * AGG_R; e < end0; e += 4) {   // rare deg>24 tail
      if (sub < end0 - e) {
        int s = srcs[e + sub];
        f16x8 g = *(const f16x8*)(feat + (size_t)s * 128 + n15 * 8);
#pragma unroll
        for (int j = 0; j < 8; ++j) acc0[j] += (float)g[j];
      }
    }
    for (int e = beg1 + 4 * AGG_R; e < end1; e += 4) {
      if (sub < end1 - e) {
        int s = srcs[e + sub];
        f16x8 g = *(const f16x8*)(feat + (size_t)s * 128 + n15 * 8);
#pragma unroll
        for (int j = 0; j < 8; ++j) acc1[j] += (float)g[j];
      }
    }
#pragma unroll
    for (int j = 0; j < 8; ++j) {
      acc0[j] += __shfl_xor(acc0[j], 16);
      acc0[j] += __shfl_xor(acc0[j], 32);
      acc1[j] += __shfl_xor(acc1[j], 16);
      acc1[j] += __shfl_xor(acc1[j], 32);
    }
    if (sub == 0) {
      float inv = 1.0f / fmaxf((float)deg0, 1.0f);
      f16x8 o;
#pragma unroll
      for (int j = 0; j < 8; ++j) o[j] = (f16)(acc0[j] * inv);
      *(f16x8*)(lds + 4096 + ln0 * 128 + ((n15 ^ (ln0 & 15)) << 3)) = o;
    } else if (sub == 1) {
      float inv = 1.0f / fmaxf((float)deg1, 1.0f);
      int ln1 = ln0 + 1;
      f16x8 o;
#pragma unroll
      for (int j = 0; j < 8; ++j) o[j] = (f16)(acc1[j] * inv);
      *(f16x8*)(lds + 4096 + ln1 * 128 + ((n15 ^ (ln1 & 15)) << 3)) = o;
    }
  }
  __syncthreads();   // means + stage round 0 visible

  // ---- Phase B: gemm. wave -> (rowgroup rg, colhalf ch); 16 rows x 64 cols.
  int rg = wave & 1, ch = wave >> 1;
  int rowl = rg * 16 + n15;
  int colb = ch * 64;

  f16x8 a[8];
#pragma unroll
  for (int kk = 0; kk < 4; ++kk)    // mean part (k 0..127) from swizzled LDS
    a[kk] = *(const f16x8*)(lds + 4096 + rowl * 128 + (((kk * 4 + sub) ^ n15) << 3));
  {
    int node = base + rowl; if (node >= n) node = n - 1;   // clamped tail load
    const f16* bp = feat + (size_t)node * 128 + sub * 8;
#pragma unroll
    for (int kk = 4; kk < 8; ++kk) a[kk] = *(const f16x8*)(bp + (kk - 4) * 32);
  }

  f32x4 acc[4] = {};
#pragma unroll
  for (int q = 0; q < 8; ++q) {
    if (q) {
      __syncthreads();   // all waves done with previous round's B
      ((f16x8*)lds)[tid]       = ((const f16x8*)WtA)[q * 512 + tid];
      ((f16x8*)lds)[256 + tid] = ((const f16x8*)WtA)[q * 512 + 256 + tid];
      __syncthreads();   // round q staged
    }
#pragma unroll
    for (int t = 0; t < 4; ++t) {
      f16x8 bfr = ((const f16x8*)lds)[sub * 128 + colb + t * 16 + n15];
      acc[t] = __builtin_amdgcn_mfma_f32_16x16x32_f16(a[q], bfr, acc[t], 0, 0, 0);
    }
  }

  if (!HEAD) {
    // epilogue: x1 = relu(acc + bA) -> f16 out
#pragma unroll
    for (int t = 0; t < 4; ++t) {
      float bv = bA[colb + t * 16 + n15];
#pragma unroll
      for (int i = 0; i < 4; ++i) {
        int row = base + rg * 16 + sub * 4 + i;
        if (row < n) {
          float v = fmaxf(acc[t][i] + bv, 0.f);
          ((f16*)outp)[(size_t)row * 128 + colb + t * 16 + n15] = (f16)v;
        }
      }
    }
  } else {
    // x2 = relu(acc + bA) -> swizzled LDS tile (own region; no conflict)
#pragma unroll
    for (int t = 0; t < 4; ++t) {
      float bv = bA[colb + t * 16 + n15];
      int col = colb + t * 16 + n15;
      int cchunk = col >> 3, coff = col & 7;
#pragma unroll
      for (int i = 0; i < 4; ++i) {
        int rw = rg * 16 + sub * 4 + i;
        float v = fmaxf(acc[t][i] + bv, 0.f);
        lds[8192 + rw * 128 + (((cchunk ^ (rw & 15)) << 3) | coff)] = (f16)v;
      }
    }
    __syncthreads();   // B region free (all mfma(7) reads done); x2 visible
    ((f16x8*)lds)[tid]       = ((const f16x8*)WtB)[tid];
    ((f16x8*)lds)[256 + tid] = ((const f16x8*)WtB)[256 + tid];
    __syncthreads();   // WtB round 0 staged

    f16x8 a2[4];
#pragma unroll
    for (int kk2 = 0; kk2 < 4; ++kk2)
      a2[kk2] = *(const f16x8*)(lds + 8192 + rowl * 128 + (((kk2 * 4 + sub) ^ n15) << 3));

    f32x4 acc3[4] = {};
#pragma unroll
    for (int q = 0; q < 8; ++q) {
      if (q) {
        __syncthreads();
        ((f16x8*)lds)[tid]       = ((const f16x8*)WtB)[q * 512 + tid];
        ((f16x8*)lds)[256 + tid] = ((const f16x8*)WtB)[q * 512 + 256 + tid];
        __syncthreads();
      }
#pragma unroll
      for (int t = 0; t < 4; ++t) {
        f16x8 bfr = ((const f16x8*)lds)[sub * 128 + colb + t * 16 + n15];
        f16x8 av = (q < 4) ? a[4 + q] : a2[q - 4];   // [x1 | x2]
        acc3[t] = __builtin_amdgcn_mfma_f32_16x16x32_f16(av, bfr, acc3[t], 0, 0, 0);
      }
    }
#pragma unroll
    for (int t = 0; t < 4; ++t) {
      float bv = bB[colb + t * 16 + n15];
#pragma unroll
      for (int i = 0; i < 4; ++i) {
        int row = base + rg * 16 + sub * 4 + i;
        if (row < n)
          ((float*)outp)[(size_t)row * 128 + colb + t * 16 + n15] = acc3[t][i] + bv;
      }
    }
  }
}

extern "C" void kernel_launch(void* const* d_in, const int* in_sizes, int n_in,
                              void* d_out, int out_size, void* d_ws, size_t ws_size,
                              hipStream_t stream) {
  (void)n_in; (void)out_size; (void)ws_size;
  const float* x    = (const float*)d_in[0];
  const int*   ei   = (const int*)d_in[1];
  const float* W1l  = (const float*)d_in[2];
  const float* b1l  = (const float*)d_in[3];
  const float* W1r  = (const float*)d_in[4];
  const float* W2l  = (const float*)d_in[5];
  const float* b2l  = (const float*)d_in[6];
  const float* W2r  = (const float*)d_in[7];
  const float* Wlin = (const float*)d_in[8];
  const float* blin = (const float*)d_in[9];
  const int N = in_sizes[0] / 128;
  const int E = in_sizes[1] / 2;

  char* ws = (char*)d_ws;
  size_t o = 0;
  auto alloc = [&](size_t bytes) {
    char* p = ws + o;
    o = (o + bytes + 255) & ~(size_t)255;
    return p;
  };
  f16*  xh   = (f16*)alloc((size_t)N * 128 * 2);
  f16*  x1h  = (f16*)alloc((size_t)N * 128 * 2);
  f16*  wt   = (f16*)alloc((size_t)3 * 32768 * 2);   // wt1|wt2|wt3 contiguous
  int*  off  = (int*)alloc(((size_t)N + 1) * 4);
  int*  srcs = (int*)alloc((size_t)E * 4);
  u32*  tmp  = (u32*)alloc((size_t)E * 4);           // packed (src<<8)|dstLow
  int*  ghist= (int*)alloc(256 * RNB * 4);
  f16* wt1 = wt, *wt2 = wt + 32768, *wt3 = wt + 65536;

  const int n4 = N * 128 / 4;
  const int cb = (n4 + 255) / 256;           // convert blocks
  const int wb = (3 * 32768) / 256;          // weight blocks (384)
  const int HB = (N + 255) / 256;            // high-byte buckets (196)

  // prep (convert + weights + radix hist)
  prep_kernel<<<cb + wb + RNB, 256, 0, stream>>>(x, xh, n4, ei, ghist, E,
                                                 W1l, W1r, W2l, W2r, Wlin, wt, cb, wb);
  // CSR build (atomic-free; global prefix rebuilt inline)
  radix_scatter<<<RNB, 256, 0, stream>>>(ei, ghist, tmp, E);
  radix_bucket<<<HB, 256, 0, stream>>>(tmp, ghist, srcs, off, N, E, HB);

  const int fusedBlocks = (N + 31) / 32;     // 1563

  // layer 1 fused: x1 = relu(mean(x) @ W1_l + x @ W1_r + b1)
  fused_kernel<false><<<fusedBlocks, 256, 0, stream>>>(
      xh, off, srcs, wt1, (const f16*)nullptr, b1l, (const float*)nullptr, x1h, N);
  // layer 2 + head fused: x2 = relu(mean(x1) @ W2 + b2); out = [x1|x2] @ W3 + b3
  fused_kernel<true><<<fusedBlocks, 256, 0, stream>>>(
      x1h, off, srcs, wt2, wt3, b2l, blin, d_out, N);
}

// Round 6
// 225.017 us; speedup vs baseline: 1.2890x; 1.1108x over previous
//
#include <hip/hip_runtime.h>

// GraphSAGE 2-layer + linear head, N=50000, E=600000, C=128 everywhere.
// R15: REVERT to R11 (best measured, 225.9us) after two occupancy-theory
//      regressions. Final cost model (fits all 6 rounds):
//        fills (harness re-poison, fixed)        ~86us
//        agg x2 (per-CU miss-queue x L2/L3 lat)  ~76us
//        prep + CSR + gemm1 + gemm23 + gaps      ~60us  => ~222-226us.
// R13: launch_bounds(256,8) => VGPR cap 64, ~128MB scratch, 290us. DEAD.
// R14: launch_bounds(256,5) => VGPR 48 + ~12MB scratch, HEAD 55->67, 250us.
//      DEAD. R12's achieved Occ 29% < static cap 4-5 blocks/CU => static
//      occupancy was never binding; agg is outstanding-miss-limited.
// Ledger (all NEUTRAL or NEGATIVE - do not retry): gemm-fusion-unstaged-B
//      (R10), agg+gemm fusion (R12), LDS-shrink+reg-squeeze (R13/R14),
//      fp8 agg bytes, ILP depth, XCD-slice, slice-agg, col-split gemm.
// Wins that ARE load-bearing here: R3 prefetch-all agg; v2 64KB gemm;
//      folded scan (R10b); gemm23 fusion w/ two-half Wt3 LDS stage (R11);
//      32-bit packed radix tmp; 3-role prep.

typedef _Float16 f16;
typedef unsigned int u32;
typedef __attribute__((ext_vector_type(4))) _Float16 f16x4;
typedef __attribute__((ext_vector_type(8))) _Float16 f16x8;
typedef __attribute__((ext_vector_type(4))) float f32x4;

#define RNB 128   // radix blocks (256 bins x 128 = 32768 hist entries)

// ---- prep: [0,cb) convert x -> f16 | [cb,cb+wb) weights | rest: radix hist
// weights k-chunked transposed, 3 tables contiguous (32768 f16 each):
// wt[w][(chunk*128 + n)*8 + j] = W_w[k=chunk*8+j][n], W = [WA;WB] stacked.
__global__ void prep_kernel(const float* __restrict__ x, f16* __restrict__ xh, int n4,
                            const int* __restrict__ ei, int* __restrict__ ghist, int E,
                            const float* __restrict__ W1l, const float* __restrict__ W1r,
                            const float* __restrict__ W2l, const float* __restrict__ W2r,
                            const float* __restrict__ Wlin, f16* __restrict__ wt,
                            int cb, int wb) {
  int b = blockIdx.x;
  if (b < cb) {
    int i = b * 256 + threadIdx.x;
    if (i < n4) {
      const float4 v = ((const float4*)x)[i];
      f16x4 h = { (f16)v.x, (f16)v.y, (f16)v.z, (f16)v.w };
      ((f16x4*)xh)[i] = h;
    }
  } else if (b < cb + wb) {
    int tid = (b - cb) * 256 + threadIdx.x;   // 0 .. 3*32768
    int w = tid >> 15, idx = tid & 32767;
    int j = idx & 7, n = (idx >> 3) & 127, chunk = idx >> 10;
    int k = chunk * 8 + j;
    float v;
    if (w == 0) v = (k < 128) ? W1l[k * 128 + n] : W1r[(k - 128) * 128 + n];
    else if (w == 1) v = (k < 128) ? W2l[k * 128 + n] : W2r[(k - 128) * 128 + n];
    else v = Wlin[k * 128 + n];
    wt[tid] = (f16)v;
  } else {
    __shared__ int h[256];
    int tid = threadIdx.x, rb = b - cb - wb;   // 0..RNB-1
    h[tid] = 0;
    __syncthreads();
    int per = (E + RNB - 1) / RNB;
    int s = rb * per, e = s + per; if (e > E) e = E;
    for (int i = s + tid; i < e; i += 256) atomicAdd(&h[ei[E + i] >> 8], 1);
    __syncthreads();
    ghist[tid * RNB + rb] = h[tid];
  }
}

// shfl-based exclusive scan over 256 threads (4 waves); one barrier.
__device__ inline int block_excl_scan256(int v, int* ws) {
  int lane = threadIdx.x & 63, w = threadIdx.x >> 6;
  int incl = v;
#pragma unroll
  for (int o = 1; o < 64; o <<= 1) {
    int u = __shfl_up(incl, o);
    if (lane >= o) incl += u;
  }
  if (lane == 63) ws[w] = incl;
  __syncthreads();
  int base = 0;
#pragma unroll
  for (int i = 0; i < 4; ++i) base += (i < w) ? ws[i] : 0;
  return base + incl - v;
}

// deterministic scatter into per-(block,bin) ranges; LDS cursors only.
// Global prefix rebuilt inline from ghist (row-sum + 256-scan) — no scan kernel.
// tmp entry = (src<<8) | (dst & 255)  -- 32-bit, requires src < 2^24.
__global__ void radix_scatter(const int* __restrict__ ei, const int* __restrict__ ghist,
                              u32* __restrict__ tmp, int E) {
  __shared__ int cur[256];
  __shared__ int ws[4];
  int tid = threadIdx.x, b = blockIdx.x;
  const int* row = ghist + tid * RNB;
  int part = 0, rest = 0;
  for (int i = 0; i < b; ++i) part += row[i];          // entries of my bin in blocks < b
  for (int i = b; i < RNB; ++i) rest += row[i];
  int total = part + rest;
  int excl = block_excl_scan256(total, ws);            // entries of bins < mine
  cur[tid] = excl + part;
  __syncthreads();
  int per = (E + RNB - 1) / RNB;
  int s = b * per, e = s + per; if (e > E) e = E;
  for (int i = s + tid; i < e; i += 256) {
    int d = ei[E + i], sr = ei[i];
    int pos = atomicAdd(&cur[d >> 8], 1);              // LDS atomic
    tmp[pos] = ((u32)sr << 8) | (u32)(d & 255);
  }
}

// one block per high-byte bucket: LDS low-byte hist + scan -> off[] + srcs.
__global__ void radix_bucket(const u32* __restrict__ tmp, const int* __restrict__ ghist,
                             int* __restrict__ srcs, int* __restrict__ off,
                             int N, int E, int HB) {
  __shared__ int h[256], sc[256], cur[256];
  __shared__ int bsc[257];
  __shared__ int ws[4];
  int tid = threadIdx.x, hb = blockIdx.x;
  // rebuild global per-bin prefix from ghist
  const int* row = ghist + tid * RNB;
  int total = 0;
#pragma unroll 4
  for (int i = 0; i < RNB; ++i) total += row[i];
  int excl = block_excl_scan256(total, ws);
  bsc[tid] = excl;
  if (tid == 255) bsc[256] = E;
  h[tid] = 0;
  __syncthreads();
  int start = bsc[hb];
  int end = bsc[hb + 1];
  for (int i = start + tid; i < end; i += 256) atomicAdd(&h[tmp[i] & 255u], 1);
  __syncthreads();
  sc[tid] = h[tid];
  __syncthreads();
  for (int o = 1; o < 256; o <<= 1) {
    int u = (tid >= o) ? sc[tid - o] : 0;
    __syncthreads();
    sc[tid] += u;
    __syncthreads();
  }
  int exclb = sc[tid] - h[tid];
  int v = (hb << 8) + tid;
  if (v < N) off[v] = start + exclb;
  if (hb == 0 && tid == 0) off[N] = E;
  cur[tid] = start + exclb;
  __syncthreads();
  for (int i = start + tid; i < end; i += 256) {
    u32 p = tmp[i];
    int pos = atomicAdd(&cur[p & 255u], 1);   // LDS atomic
    srcs[pos] = (int)(p >> 8);
  }
}

// agg v3 (R3, best measured): wave = 2 nodes; lane = slot(sub) x chgroup(n15).
// Prefetch up to 24 edge indices/node, then all gathers, single drain,
// fp32 accum, cross-slot shfl reduce, f16 mean out. NO launch_bounds:
// natural 64 VGPR, no LDS => max occupancy, no spill (R13/R14 lesson).
#define AGG_R 6
__global__ void aggregate_kernel(const f16* __restrict__ feat, const int* __restrict__ off,
                                 const int* __restrict__ srcs, f16* __restrict__ meanf, int n) {
  int pair = (int)((blockIdx.x * blockDim.x + threadIdx.x) >> 6);
  int w0 = pair * 2;
  if (w0 >= n) return;
  int w1 = w0 + 1;
  int lane = threadIdx.x & 63;
  int sub = lane >> 4, n15 = lane & 15;
  int beg0 = off[w0], end0 = off[w0 + 1];
  int beg1 = end0;                              // CSR contiguity
  int end1 = (w1 < n) ? off[w1 + 1] : end0;
  int deg0 = end0 - beg0, deg1 = end1 - beg1;

  int s0[AGG_R], s1[AGG_R];
  bool v0[AGG_R], v1[AGG_R];
#pragma unroll
  for (int k = 0; k < AGG_R; ++k) {
    int p = 4 * k + sub;
    v0[k] = p < deg0;  s0[k] = v0[k] ? srcs[beg0 + p] : 0;
    v1[k] = p < deg1;  s1[k] = v1[k] ? srcs[beg1 + p] : 0;
  }
  f16x8 g0[AGG_R], g1[AGG_R];
#pragma unroll
  for (int k = 0; k < AGG_R; ++k) {
    if (v0[k]) g0[k] = *(const f16x8*)(feat + (size_t)s0[k] * 128 + n15 * 8);
    if (v1[k]) g1[k] = *(const f16x8*)(feat + (size_t)s1[k] * 128 + n15 * 8);
  }
  float acc0[8] = {}, acc1[8] = {};
#pragma unroll
  for (int k = 0; k < AGG_R; ++k) {
    if (v0[k]) {
#pragma unroll
      for (int j = 0; j < 8; ++j) acc0[j] += (float)g0[k][j];
    }
    if (v1[k]) {
#pragma unroll
      for (int j = 0; j < 8; ++j) acc1[j] += (float)g1[k][j];
    }
  }
  for (int e = beg0 + 4 * AGG_R; e < end0; e += 4) {   // rare deg>24 tail
    if (sub < end0 - e) {
      int s = srcs[e + sub];
      f16x8 g = *(const f16x8*)(feat + (size_t)s * 128 + n15 * 8);
#pragma unroll
      for (int j = 0; j < 8; ++j) acc0[j] += (float)g[j];
    }
  }
  for (int e = beg1 + 4 * AGG_R; e < end1; e += 4) {
    if (sub < end1 - e) {
      int s = srcs[e + sub];
      f16x8 g = *(const f16x8*)(feat + (size_t)s * 128 + n15 * 8);
#pragma unroll
      for (int j = 0; j < 8; ++j) acc1[j] += (float)g[j];
    }
  }
#pragma unroll
  for (int j = 0; j < 8; ++j) {
    acc0[j] += __shfl_xor(acc0[j], 16);
    acc0[j] += __shfl_xor(acc0[j], 32);
    acc1[j] += __shfl_xor(acc1[j], 16);
    acc1[j] += __shfl_xor(acc1[j], 32);
  }
  if (sub == 0) {
    float inv = 1.0f / fmaxf((float)deg0, 1.0f);
    f16x8 o;
#pragma unroll
    for (int j = 0; j < 8; ++j) o[j] = (f16)(acc0[j] * inv);
    *(f16x8*)(meanf + (size_t)w0 * 128 + n15 * 8) = o;
  } else if (sub == 1 && w1 < n) {
    float inv = 1.0f / fmaxf((float)deg1, 1.0f);
    f16x8 o;
#pragma unroll
    for (int j = 0; j < 8; ++j) o[j] = (f16)(acc1[j] * inv);
    *(f16x8*)(meanf + (size_t)w1 * 128 + n15 * 8) = o;
  }
}

// GEMM v2 (best measured, layer 1): Y[M,128] = act([U|V][M,256] @ W + bias);
// Wt k-chunked in 64KB LDS; 4 waves; wave = 32 rows x 128 cols.
template <bool RELU, bool OUT16>
__global__ __launch_bounds__(256, 2) void gemm_kernel(
    const f16* __restrict__ U, const f16* __restrict__ V, const f16* __restrict__ Wt,
    const float* __restrict__ bias, void* __restrict__ outp, int M) {
  __shared__ f16 ldsb[32768];   // 64 KB
  int tid = threadIdx.x;
  int wave = tid >> 6, lane = tid & 63;
  int quad = lane >> 4, n15 = lane & 15;
  int m0 = blockIdx.x * 128 + wave * 32;
  int kq = quad * 8;

  f16x8 a[2][8];
#pragma unroll
  for (int r = 0; r < 2; ++r) {
    int row = m0 + r * 16 + n15;
    int rowc = row < M ? row : M - 1;   // clamp tail loads (stores guarded)
    const f16* bu = U + (size_t)rowc * 128 + kq;
    const f16* bv = V + (size_t)rowc * 128 + kq;
#pragma unroll
    for (int kk = 0; kk < 4; ++kk) a[r][kk] = *(const f16x8*)(bu + kk * 32);
#pragma unroll
    for (int kk = 4; kk < 8; ++kk) a[r][kk] = *(const f16x8*)(bv + (kk - 4) * 32);
  }

#pragma unroll
  for (int it = 0; it < 16; ++it) {
    int idx = it * 256 + tid;
    ((f16x8*)ldsb)[idx] = ((const f16x8*)Wt)[idx];
  }
  __syncthreads();

  f32x4 acc[2][8] = {};
#pragma unroll
  for (int kk = 0; kk < 8; ++kk) {
#pragma unroll
    for (int t = 0; t < 8; ++t) {
      f16x8 b = ((const f16x8*)ldsb)[(kk * 4 + quad) * 128 + t * 16 + n15];
#pragma unroll
      for (int r = 0; r < 2; ++r)
        acc[r][t] = __builtin_amdgcn_mfma_f32_16x16x32_f16(a[r][kk], b, acc[r][t], 0, 0, 0);
    }
  }

  int rbase0 = m0 + quad * 4;
#pragma unroll
  for (int t = 0; t < 8; ++t) {
    float bv = bias[t * 16 + n15];
#pragma unroll
    for (int r = 0; r < 2; ++r) {
#pragma unroll
      for (int i = 0; i < 4; ++i) {
        int row = rbase0 + r * 16 + i;
        if (row < M) {
          float v = acc[r][t][i] + bv;
          if (RELU) v = fmaxf(v, 0.f);
          size_t idx = (size_t)row * 128 + t * 16 + n15;
          if (OUT16) ((f16*)outp)[idx] = (f16)v;
          else       ((float*)outp)[idx] = v;
        }
      }
    }
  }
}

// FUSED gemm2+gemm3: x2 = relu([mh|x1] @ W2 + b2) ; out = [x1|x2] @ W3 + b3.
// x1 A-fragments (a[r][4..7]) reused in-register for the head. x2 never
// round-trips through global: C->A transpose via XOR-swizzled 32KB LDS tile.
// Wt3 staged through LDS in two 32KB halves (upper buffer), top half
// overlapped against the lower-chunk layer-2 MFMAs.
__global__ __launch_bounds__(256, 2) void gemm23_kernel(
    const f16* __restrict__ U,      // mh = mean(x1)
    const f16* __restrict__ V,      // x1h
    const f16* __restrict__ Wt2, const f16* __restrict__ Wt3,
    const float* __restrict__ b2, const float* __restrict__ b3,
    float* __restrict__ out, int M) {
  __shared__ f16 ldsb[32768];   // 64 KB; lower 32KB: Wt2lo -> x2 tile,
                                //         upper 32KB: Wt2hi -> Wt3top -> Wt3bot
  int tid = threadIdx.x;
  int wave = tid >> 6, lane = tid & 63;
  int quad = lane >> 4, n15 = lane & 15;
  int m0 = blockIdx.x * 128 + wave * 32;
  int kq = quad * 8;

  f16x8 a[2][8];
#pragma unroll
  for (int r = 0; r < 2; ++r) {
    int row = m0 + r * 16 + n15;
    int rowc = row < M ? row : M - 1;
    const f16* bu = U + (size_t)rowc * 128 + kq;
    const f16* bv = V + (size_t)rowc * 128 + kq;
#pragma unroll
    for (int kk = 0; kk < 4; ++kk) a[r][kk] = *(const f16x8*)(bu + kk * 32);
#pragma unroll
    for (int kk = 4; kk < 8; ++kk) a[r][kk] = *(const f16x8*)(bv + (kk - 4) * 32);
  }

#pragma unroll
  for (int it = 0; it < 16; ++it) {
    int idx = it * 256 + tid;
    ((f16x8*)ldsb)[idx] = ((const f16x8*)Wt2)[idx];
  }
  __syncthreads();

  // ---- layer 2 MFMA, UPPER chunks first (kk=4..7 -> chunks 16..31)
  f32x4 acc[2][8] = {};
#pragma unroll
  for (int kk = 4; kk < 8; ++kk) {
#pragma unroll
    for (int t = 0; t < 8; ++t) {
      f16x8 b = ((const f16x8*)ldsb)[(kk * 4 + quad) * 128 + t * 16 + n15];
#pragma unroll
      for (int r = 0; r < 2; ++r)
        acc[r][t] = __builtin_amdgcn_mfma_f32_16x16x32_f16(a[r][kk], b, acc[r][t], 0, 0, 0);
    }
  }
  __syncthreads();   // upper 32KB free

  // stage Wt3 TOP half into upper 32KB; overlaps with lower-chunk MFMAs below
#pragma unroll
  for (int it = 0; it < 8; ++it) {
    int idx = it * 256 + tid;
    ((f16x8*)ldsb)[2048 + idx] = ((const f16x8*)Wt3)[idx];
  }
  // ---- layer 2 MFMA, LOWER chunks (kk=0..3)
#pragma unroll
  for (int kk = 0; kk < 4; ++kk) {
#pragma unroll
    for (int t = 0; t < 8; ++t) {
      f16x8 b = ((const f16x8*)ldsb)[(kk * 4 + quad) * 128 + t * 16 + n15];
#pragma unroll
      for (int r = 0; r < 2; ++r)
        acc[r][t] = __builtin_amdgcn_mfma_f32_16x16x32_f16(a[r][kk], b, acc[r][t], 0, 0, 0);
    }
  }
  __syncthreads();   // lower 32KB free; Wt3top visible to all waves

  // ---- write relu(x2)+b2 as f16 into XOR-swizzled LDS tile [128][128] (lower)
#pragma unroll
  for (int t = 0; t < 8; ++t) {
    float bv = b2[t * 16 + n15];
    int chunk = t * 2 + (n15 >> 3);
    int offc = n15 & 7;
#pragma unroll
    for (int r = 0; r < 2; ++r) {
#pragma unroll
      for (int i = 0; i < 4; ++i) {
        int rowl = wave * 32 + r * 16 + quad * 4 + i;
        float v = fmaxf(acc[r][t][i] + bv, 0.f);
        ldsb[rowl * 128 + (((chunk ^ (rowl & 15)) << 3) | offc)] = (f16)v;
      }
    }
  }
  __syncthreads();

  // ---- read x2 A-frags from lower (conflict-free b128 via swizzle)
  f16x8 a2[2][4];
#pragma unroll
  for (int r = 0; r < 2; ++r) {
    int rowl = wave * 32 + r * 16 + n15;
#pragma unroll
    for (int kk2 = 0; kk2 < 4; ++kk2) {
      int chunk = kk2 * 4 + quad;
      a2[r][kk2] = *(const f16x8*)(ldsb + rowl * 128 + ((chunk ^ (rowl & 15)) << 3));
    }
  }

  // ---- head part 1: x1 (regs) x Wt3top (upper LDS), kk=0..3
  f32x4 acc3[2][8] = {};
#pragma unroll
  for (int kk = 0; kk < 4; ++kk) {
#pragma unroll
    for (int t = 0; t < 8; ++t) {
      f16x8 b = ((const f16x8*)ldsb)[2048 + (kk * 4 + quad) * 128 + t * 16 + n15];
#pragma unroll
      for (int r = 0; r < 2; ++r)
        acc3[r][t] = __builtin_amdgcn_mfma_f32_16x16x32_f16(a[r][4 + kk], b, acc3[r][t], 0, 0, 0);
    }
  }
  __syncthreads();   // upper free again

  // stage Wt3 BOTTOM half into upper 32KB
#pragma unroll
  for (int it = 0; it < 8; ++it) {
    int idx = it * 256 + tid;
    ((f16x8*)ldsb)[2048 + idx] = ((const f16x8*)Wt3)[2048 + idx];
  }
  __syncthreads();

  // ---- head part 2: x2 (LDS lower, in a2) x Wt3bot (upper LDS), kk=4..7
#pragma unroll
  for (int kk = 4; kk < 8; ++kk) {
#pragma unroll
    for (int t = 0; t < 8; ++t) {
      f16x8 b = ((const f16x8*)ldsb)[2048 + ((kk - 4) * 4 + quad) * 128 + t * 16 + n15];
#pragma unroll
      for (int r = 0; r < 2; ++r)
        acc3[r][t] = __builtin_amdgcn_mfma_f32_16x16x32_f16(a2[r][kk - 4], b, acc3[r][t], 0, 0, 0);
    }
  }

  int rbase0 = m0 + quad * 4;
#pragma unroll
  for (int t = 0; t < 8; ++t) {
    float bv = b3[t * 16 + n15];
#pragma unroll
    for (int r = 0; r < 2; ++r) {
#pragma unroll
      for (int i = 0; i < 4; ++i) {
        int row = rbase0 + r * 16 + i;
        if (row < M)
          out[(size_t)row * 128 + t * 16 + n15] = acc3[r][t][i] + bv;
      }
    }
  }
}

extern "C" void kernel_launch(void* const* d_in, const int* in_sizes, int n_in,
                              void* d_out, int out_size, void* d_ws, size_t ws_size,
                              hipStream_t stream) {
  (void)n_in; (void)out_size; (void)ws_size;
  const float* x    = (const float*)d_in[0];
  const int*   ei   = (const int*)d_in[1];
  const float* W1l  = (const float*)d_in[2];
  const float* b1l  = (const float*)d_in[3];
  const float* W1r  = (const float*)d_in[4];
  const float* W2l  = (const float*)d_in[5];
  const float* b2l  = (const float*)d_in[6];
  const float* W2r  = (const float*)d_in[7];
  const float* Wlin = (const float*)d_in[8];
  const float* blin = (const float*)d_in[9];
  const int N = in_sizes[0] / 128;
  const int E = in_sizes[1] / 2;

  char* ws = (char*)d_ws;
  size_t o = 0;
  auto alloc = [&](size_t bytes) {
    char* p = ws + o;
    o = (o + bytes + 255) & ~(size_t)255;
    return p;
  };
  f16*  xh   = (f16*)alloc((size_t)N * 128 * 2);
  f16*  x1h  = (f16*)alloc((size_t)N * 128 * 2);
  f16*  mh   = (f16*)alloc((size_t)N * 128 * 2);
  f16*  wt   = (f16*)alloc((size_t)3 * 32768 * 2);   // wt1|wt2|wt3 contiguous
  int*  off  = (int*)alloc(((size_t)N + 1) * 4);
  int*  srcs = (int*)alloc((size_t)E * 4);
  u32*  tmp  = (u32*)alloc((size_t)E * 4);           // packed (src<<8)|dstLow
  int*  ghist= (int*)alloc(256 * RNB * 4);
  f16* wt1 = wt, *wt2 = wt + 32768, *wt3 = wt + 65536;

  const int n4 = N * 128 / 4;
  const int cb = (n4 + 255) / 256;           // convert blocks
  const int wb = (3 * 32768) / 256;          // weight blocks (384)
  const int HB = (N + 255) / 256;            // high-byte buckets (196)

  // prep (convert + weights + radix hist)
  prep_kernel<<<cb + wb + RNB, 256, 0, stream>>>(x, xh, n4, ei, ghist, E,
                                                 W1l, W1r, W2l, W2r, Wlin, wt, cb, wb);
  // CSR build (atomic-free; global prefix rebuilt inline — no scan kernel)
  radix_scatter<<<RNB, 256, 0, stream>>>(ei, ghist, tmp, E);
  radix_bucket<<<HB, 256, 0, stream>>>(tmp, ghist, srcs, off, N, E, HB);

  const int aggBlocks  = ((N + 1) / 2 + 3) / 4;   // 2 nodes/wave, 4 waves/block
  const int gemmBlocks = (N + 127) / 128;         // 128 rows/block

  // layer 1: x1 = relu(mean(x) @ W1_l + x @ W1_r + b1)
  aggregate_kernel<<<aggBlocks, 256, 0, stream>>>(xh, off, srcs, mh, N);
  gemm_kernel<true, true><<<gemmBlocks, 256, 0, stream>>>(mh, xh, wt1, b1l, x1h, N);
  // layer 2 + head fused: x2 = relu(mean(x1) @ W2 + b2); out = [x1|x2] @ W3 + b3
  aggregate_kernel<<<aggBlocks, 256, 0, stream>>>(x1h, off, srcs, mh, N);
  gemm23_kernel<<<gemmBlocks, 256, 0, stream>>>(mh, x1h, wt2, wt3, b2l, blin,
                                                (float*)d_out, N);
}